// Round 1
// baseline (219.530 us; speedup 1.0000x reference)
//
#include <hip/hip_runtime.h>
#include <math.h>

// Problem constants
#define B_SZ 1024
#define Z_DIM 512
#define A_DIM 8
#define AH 64
#define ZH 512
#define NNEG 99          // n-1 = min(100,B)-1
#define ROWLEN (B_SZ + NNEG)   // 1123
#define INV_T 10.0f

// ---------------------------------------------------------------------------
// h_a0[j,t] = relu(actions[j]@Wa + ba)[t], j in [0,1024), t in [0,64)
__global__ __launch_bounds__(256) void ha_kernel(const float* __restrict__ actions,
                                                 const float* __restrict__ Wa,
                                                 const float* __restrict__ ba,
                                                 float* __restrict__ ha) {
    int idx = blockIdx.x * 256 + threadIdx.x;   // 0..65535
    int j = idx >> 6, t = idx & 63;
    float s = ba[t];
#pragma unroll
    for (int k = 0; k < A_DIM; ++k) s += actions[j * A_DIM + k] * Wa[k * AH + t];
    ha[idx] = fmaxf(s, 0.0f);
}

// g[j,c] = sum_t ha[j,t] * W1[512+t, c]
__global__ __launch_bounds__(256) void g_kernel(const float* __restrict__ ha,
                                                const float* __restrict__ W1,
                                                float* __restrict__ g) {
    int bid = blockIdx.x;              // 2048 blocks
    int j = bid >> 1;
    int c = ((bid & 1) << 8) + threadIdx.x;
    __shared__ float sha[AH];
    if (threadIdx.x < AH) sha[threadIdx.x] = ha[j * AH + threadIdx.x];
    __syncthreads();
    float s = 0.0f;
#pragma unroll
    for (int t = 0; t < AH; ++t) s += sha[t] * W1[(Z_DIM + t) * ZH + c];
    g[j * ZH + c] = s;
}

// ---------------------------------------------------------------------------
// Tiled fp32 GEMM. TRANSB=false: C = A[MxK] @ B[KxN] (+bias[n])
//                  TRANSB=true : C = A[MxK] @ B[NxK]^T (+bias[n])
// M,N multiples of 64; K multiple of 32.
template <bool TRANSB>
__global__ __launch_bounds__(256) void sgemm_kernel(const float* __restrict__ A,
                                                    const float* __restrict__ B,
                                                    const float* __restrict__ bias,
                                                    float* __restrict__ C,
                                                    int M, int N, int K) {
    constexpr int BM = 64, BN = 64, BK = 32;
    __shared__ float As[BK][BM + 1];
    __shared__ float Bs[BK][BN + 1];
    int bm0 = blockIdx.y * BM;
    int bn0 = blockIdx.x * BN;
    int tid = threadIdx.x;
    int tm = (tid >> 4) << 2;   // 0..60
    int tn = (tid & 15) << 2;   // 0..60
    float acc[4][4] = {};
    for (int k0 = 0; k0 < K; k0 += BK) {
#pragma unroll
        for (int i = 0; i < 8; ++i) {
            int lin = tid + i * 256;
            int r = lin >> 5;          // 0..63 (m)
            int c = lin & 31;          // 0..31 (k)
            As[c][r] = A[(bm0 + r) * K + k0 + c];
        }
#pragma unroll
        for (int i = 0; i < 8; ++i) {
            int lin = tid + i * 256;
            if (TRANSB) {
                int r = lin >> 5;      // n
                int c = lin & 31;      // k
                Bs[c][r] = B[(bn0 + r) * K + k0 + c];
            } else {
                int r = lin >> 6;      // k
                int c = lin & 63;      // n
                Bs[r][c] = B[(k0 + r) * N + bn0 + c];
            }
        }
        __syncthreads();
#pragma unroll
        for (int k = 0; k < BK; ++k) {
            float a[4], b[4];
#pragma unroll
            for (int i = 0; i < 4; ++i) a[i] = As[k][tm + i];
#pragma unroll
            for (int j = 0; j < 4; ++j) b[j] = Bs[k][tn + j];
#pragma unroll
            for (int i = 0; i < 4; ++i)
#pragma unroll
                for (int j = 0; j < 4; ++j) acc[i][j] += a[i] * b[j];
        }
        __syncthreads();
    }
#pragma unroll
    for (int i = 0; i < 4; ++i) {
        int r = bm0 + tm + i;
#pragma unroll
        for (int j = 0; j < 4; ++j) {
            int c = bn0 + tn + j;
            float v = acc[i][j];
            if (bias) v += bias[c];
            C[r * N + c] = v;
        }
    }
}

// ---------------------------------------------------------------------------
// Per-row fused kernel: builds the 1123-wide row (sim | neg_sim), then
// max / logsumexp / rank-count; atomics into acc[4].
__global__ __launch_bounds__(256) void row_kernel(const float* __restrict__ sim,
                                                  const float* __restrict__ u,
                                                  const float* __restrict__ v,
                                                  const float* __restrict__ g,
                                                  const float* __restrict__ z,
                                                  const float* __restrict__ z_next,
                                                  const float* __restrict__ b2,
                                                  float* __restrict__ acc) {
    int b = blockIdx.x;
    int tid = threadIdx.x;
    int wave = tid >> 6, lane = tid & 63;
    __shared__ float su[ZH];
    __shared__ float sv[ZH];
    __shared__ float row[ROWLEN];
    __shared__ float redc0[4], redmax[4], redes[4];
    __shared__ int redcnt[4];

    // stage u,v rows; sim row; c0 partial
    for (int t = tid; t < ZH; t += 256) {
        su[t] = u[b * ZH + t];
        sv[t] = v[b * ZH + t];
    }
    float p = 0.0f;
    for (int k = tid; k < Z_DIM; k += 256)
        p += (z[b * Z_DIM + k] + b2[k]) * z_next[b * Z_DIM + k];
    for (int off = 32; off; off >>= 1) p += __shfl_down(p, off);
    if (lane == 0) redc0[wave] = p;
    for (int j = tid; j < B_SZ; j += 256) row[j] = sim[b * B_SZ + j];
    __syncthreads();

    float c0 = redc0[0] + redc0[1] + redc0[2] + redc0[3];

    // neg sims: each wave handles shifts s = 1+wave, 1+wave+4, ...
    for (int s = 1 + wave; s <= NNEG; s += 4) {
        int jr = (b + s) & (B_SZ - 1);
        const float* gr = g + jr * ZH;
        float d = 0.0f;
#pragma unroll
        for (int i = 0; i < 8; ++i) {
            int t = lane + i * 64;
            float hv = su[t] + gr[t];
            hv = hv > 0.0f ? hv : 0.0f;
            d += hv * sv[t];
        }
        for (int off = 32; off; off >>= 1) d += __shfl_down(d, off);
        if (lane == 0) row[B_SZ + s - 1] = c0 + d;
    }
    __syncthreads();

    float diag = row[b];
    float m = -3.4e38f;
    for (int j = tid; j < ROWLEN; j += 256) m = fmaxf(m, row[j]);
    for (int off = 32; off; off >>= 1) m = fmaxf(m, __shfl_down(m, off));
    if (lane == 0) redmax[wave] = m;
    __syncthreads();
    m = fmaxf(fmaxf(redmax[0], redmax[1]), fmaxf(redmax[2], redmax[3]));

    float es = 0.0f;
    int cnt = 0;
    for (int j = tid; j < ROWLEN; j += 256) {
        float x = row[j];
        es += __expf((x - m) * INV_T);
        if (x > diag) cnt++;
        else if (j < b && x == diag) cnt++;   // top_k tie-break: lower index wins
    }
    for (int off = 32; off; off >>= 1) {
        es += __shfl_down(es, off);
        cnt += __shfl_down(cnt, off);
    }
    __syncthreads();
    if (lane == 0) { redes[wave] = es; redcnt[wave] = cnt; }
    __syncthreads();
    if (tid == 0) {
        float esum = redes[0] + redes[1] + redes[2] + redes[3];
        int rank = redcnt[0] + redcnt[1] + redcnt[2] + redcnt[3];
        float loss_b = (m - diag) * INV_T + logf(esum);
        atomicAdd(&acc[0], loss_b);
        if (rank < 1) atomicAdd(&acc[1], 1.0f);
        if (rank < 3) atomicAdd(&acc[2], 1.0f);
        if (rank < 10) atomicAdd(&acc[3], 1.0f);
    }
}

__global__ void finalize_kernel(const float* __restrict__ acc, float* __restrict__ out) {
    int t = threadIdx.x;
    if (t < 4) out[t] = acc[t] * (1.0f / (float)B_SZ);
}

// ---------------------------------------------------------------------------
extern "C" void kernel_launch(void* const* d_in, const int* in_sizes, int n_in,
                              void* d_out, int out_size, void* d_ws, size_t ws_size,
                              hipStream_t stream) {
    const float* z          = (const float*)d_in[0];
    const float* z_next     = (const float*)d_in[1];
    const float* z_next_hat = (const float*)d_in[2];
    const float* actions    = (const float*)d_in[3];
    const float* Wa         = (const float*)d_in[4];
    const float* ba         = (const float*)d_in[5];
    const float* W1         = (const float*)d_in[6];
    const float* b1         = (const float*)d_in[7];
    const float* W2         = (const float*)d_in[8];
    const float* b2         = (const float*)d_in[9];
    float* out = (float*)d_out;

    float* ws  = (float*)d_ws;
    float* sim = ws;                         // 1024*1024
    float* u   = sim + B_SZ * B_SZ;          // 1024*512
    float* v   = u + B_SZ * ZH;              // 1024*512
    float* g   = v + B_SZ * ZH;              // 1024*512
    float* ha  = g + B_SZ * ZH;              // 1024*64
    float* acc = ha + B_SZ * AH;             // 4

    hipMemsetAsync(acc, 0, 4 * sizeof(float), stream);

    ha_kernel<<<256, 256, 0, stream>>>(actions, Wa, ba, ha);
    g_kernel<<<2048, 256, 0, stream>>>(ha, W1, g);
    // u = z @ W1[:512,:] + b1   (NN)
    sgemm_kernel<false><<<dim3(ZH / 64, B_SZ / 64), 256, 0, stream>>>(z, W1, b1, u, B_SZ, ZH, Z_DIM);
    // v = z_next @ W2^T          (NT)
    sgemm_kernel<true><<<dim3(ZH / 64, B_SZ / 64), 256, 0, stream>>>(z_next, W2, nullptr, v, B_SZ, ZH, Z_DIM);
    // sim = z_next @ z_next_hat^T (NT)
    sgemm_kernel<true><<<dim3(B_SZ / 64, B_SZ / 64), 256, 0, stream>>>(z_next, z_next_hat, nullptr, sim, B_SZ, B_SZ, Z_DIM);

    row_kernel<<<B_SZ, 256, 0, stream>>>(sim, u, v, g, z, z_next, b2, acc);
    finalize_kernel<<<1, 64, 0, stream>>>(acc, out);
}

// Round 2
// 140.985 us; speedup vs baseline: 1.5571x; 1.5571x over previous
//
#include <hip/hip_runtime.h>
#include <math.h>

// Problem constants
#define B_SZ 1024
#define Z_DIM 512
#define A_DIM 8
#define AH 64
#define ZH 512
#define NNEG 99               // n-1 = min(100,B)-1
#define ROWLEN (B_SZ + NNEG)  // 1123
#define INV_T 10.0f

// ---------------------------------------------------------------------------
// One launch computing all four matmuls:
//   seg0 [  0,256): sim = z_next @ z_next_hat^T          [1024x1024, K=512]
//   seg1 [256,384): u   = z @ W1[:512,:] + b1            [1024x512,  K=512]
//   seg2 [384,512): v   = z_next @ W2^T                  [1024x512,  K=512]
//   seg3 [512,640): g   = relu(actions@Wa+ba) @ W1[512:] [1024x512,  K=64]
// 64x64 tile / block, 256 threads, 4x4 micro-tile, BK=32.
__global__ __launch_bounds__(256) void fused_gemm(
    const float* __restrict__ z, const float* __restrict__ z_next,
    const float* __restrict__ z_next_hat, const float* __restrict__ actions,
    const float* __restrict__ Wa, const float* __restrict__ ba,
    const float* __restrict__ W1, const float* __restrict__ b1,
    const float* __restrict__ W2,
    float* __restrict__ sim, float* __restrict__ u, float* __restrict__ v,
    float* __restrict__ g)
{
    constexpr int BK = 32;
    __shared__ float As[BK][68];   // [k][m], stride 68 -> 16B aligned rows
    __shared__ float Bs[BK][68];   // [k][n]
    __shared__ float sact[64][A_DIM];
    __shared__ float sWa[A_DIM * AH];
    __shared__ float sba[AH];

    const int id = blockIdx.x;
    const int tid = threadIdx.x;

    const float* A; const float* Bm; const float* bias = nullptr;
    float* C; int N, K; bool transb; int seg; int bm0, bn0;
    if (id < 256) {
        seg = 0; int t = id; bn0 = (t & 15) * 64; bm0 = (t >> 4) * 64;
        A = z_next; Bm = z_next_hat; C = sim; N = 1024; K = 512; transb = true;
    } else if (id < 384) {
        seg = 1; int t = id - 256; bn0 = (t & 7) * 64; bm0 = (t >> 3) * 64;
        A = z; Bm = W1; C = u; N = 512; K = 512; transb = false; bias = b1;
    } else if (id < 512) {
        seg = 2; int t = id - 384; bn0 = (t & 7) * 64; bm0 = (t >> 3) * 64;
        A = z_next; Bm = W2; C = v; N = 512; K = 512; transb = true;
    } else {
        seg = 3; int t = id - 512; bn0 = (t & 7) * 64; bm0 = (t >> 3) * 64;
        A = nullptr; Bm = W1 + Z_DIM * ZH; C = g; N = 512; K = 64; transb = false;
    }

    if (seg == 3) {  // stage action tile + Wa + ba for in-block A computation
        for (int i = tid; i < 64 * A_DIM; i += 256)
            (&sact[0][0])[i] = actions[bm0 * A_DIM + i];
        for (int i = tid; i < A_DIM * AH; i += 256) sWa[i] = Wa[i];
        if (tid < AH) sba[tid] = ba[tid];
    }
    __syncthreads();

    const int tm = (tid >> 4) << 2;   // 0..60
    const int tn = (tid & 15) << 2;   // 0..60
    float acc[4][4] = {};

    for (int k0 = 0; k0 < K; k0 += BK) {
        // ---- stage A tile (transposed: As[k][m]) ----
        if (seg == 3) {
#pragma unroll
            for (int i = 0; i < 8; ++i) {
                int lin = tid + i * 256;
                int c = lin & 31, r = lin >> 5;
                int kc = k0 + c;
                float val = sba[kc];
#pragma unroll
                for (int k = 0; k < A_DIM; ++k) val += sact[r][k] * sWa[k * AH + kc];
                As[c][r] = fmaxf(val, 0.0f);
            }
        } else {
#pragma unroll
            for (int i = 0; i < 2; ++i) {
                int f = tid + i * 256;          // 0..511
                int r = f >> 3, c = (f & 7) * 4;
                float4 av = *(const float4*)&A[(bm0 + r) * K + k0 + c];
                As[c + 0][r] = av.x; As[c + 1][r] = av.y;
                As[c + 2][r] = av.z; As[c + 3][r] = av.w;
            }
        }
        // ---- stage B tile (Bs[k][n]) ----
        if (transb) {
#pragma unroll
            for (int i = 0; i < 2; ++i) {
                int f = tid + i * 256;
                int r = f >> 3, c = (f & 7) * 4;    // r=n, c=k
                float4 bv = *(const float4*)&Bm[(bn0 + r) * K + k0 + c];
                Bs[c + 0][r] = bv.x; Bs[c + 1][r] = bv.y;
                Bs[c + 2][r] = bv.z; Bs[c + 3][r] = bv.w;
            }
        } else {
#pragma unroll
            for (int i = 0; i < 2; ++i) {
                int f = tid + i * 256;
                int r = f >> 4, c = (f & 15) * 4;   // r=k, c=n
                *(float4*)&Bs[r][c] = *(const float4*)&Bm[(k0 + r) * N + bn0 + c];
            }
        }
        __syncthreads();
#pragma unroll
        for (int k = 0; k < BK; ++k) {
            float4 a4 = *(const float4*)&As[k][tm];
            float4 b4 = *(const float4*)&Bs[k][tn];
            float a[4] = {a4.x, a4.y, a4.z, a4.w};
            float b[4] = {b4.x, b4.y, b4.z, b4.w};
#pragma unroll
            for (int i = 0; i < 4; ++i)
#pragma unroll
                for (int j = 0; j < 4; ++j) acc[i][j] += a[i] * b[j];
        }
        __syncthreads();
    }
#pragma unroll
    for (int i = 0; i < 4; ++i) {
        int r = bm0 + tm + i;
        float4 o = {acc[i][0], acc[i][1], acc[i][2], acc[i][3]};
        if (bias) {
            o.x += bias[bn0 + tn + 0]; o.y += bias[bn0 + tn + 1];
            o.z += bias[bn0 + tn + 2]; o.w += bias[bn0 + tn + 3];
        }
        *(float4*)&C[r * N + bn0 + tn] = o;
    }
}

// ---------------------------------------------------------------------------
// Per-row fused kernel: builds the 1123-wide row (sim | neg_sim), then
// max / logsumexp / rank-count; atomics into acc[4].
__global__ __launch_bounds__(256) void row_kernel(const float* __restrict__ sim,
                                                  const float* __restrict__ u,
                                                  const float* __restrict__ v,
                                                  const float* __restrict__ g,
                                                  const float* __restrict__ z,
                                                  const float* __restrict__ z_next,
                                                  const float* __restrict__ b2,
                                                  float* __restrict__ acc) {
    int b = blockIdx.x;
    int tid = threadIdx.x;
    int wave = tid >> 6, lane = tid & 63;
    __shared__ float su[ZH];
    __shared__ float sv[ZH];
    __shared__ float row[ROWLEN];
    __shared__ float redc0[4], redmax[4], redes[4];
    __shared__ int redcnt[4];

    // stage u,v rows; sim row; c0 partial
    {
        const float4* u4 = (const float4*)(u + b * ZH);
        const float4* v4 = (const float4*)(v + b * ZH);
        if (tid < ZH / 4) {
            *(float4*)&su[tid * 4] = u4[tid];
            *(float4*)&sv[tid * 4] = v4[tid];
        }
        const float4* s4 = (const float4*)(sim + b * B_SZ);
        *(float4*)&row[tid * 4] = s4[tid];
    }
    float p = 0.0f;
    {
        const float4* z4 = (const float4*)(z + b * Z_DIM);
        const float4* zn4 = (const float4*)(z_next + b * Z_DIM);
        const float4* b24 = (const float4*)b2;
        if (tid < Z_DIM / 4) {
            float4 a = z4[tid], c = b24[tid], n = zn4[tid];
            p = (a.x + c.x) * n.x + (a.y + c.y) * n.y + (a.z + c.z) * n.z + (a.w + c.w) * n.w;
        }
    }
    for (int off = 32; off; off >>= 1) p += __shfl_down(p, off);
    if (lane == 0) redc0[wave] = p;
    __syncthreads();

    float c0 = redc0[0] + redc0[1] + redc0[2] + redc0[3];

    // neg sims: each wave handles shifts s = 1+wave, 1+wave+4, ...
    for (int s = 1 + wave; s <= NNEG; s += 4) {
        int jr = (b + s) & (B_SZ - 1);
        const float4* gr4 = (const float4*)(g + jr * ZH);
        float d = 0.0f;
#pragma unroll
        for (int i = 0; i < 2; ++i) {
            int t4 = lane + i * 64;
            float4 gv = gr4[t4];
            float4 uv = *(const float4*)&su[t4 * 4];
            float4 vv = *(const float4*)&sv[t4 * 4];
            d += fmaxf(uv.x + gv.x, 0.0f) * vv.x;
            d += fmaxf(uv.y + gv.y, 0.0f) * vv.y;
            d += fmaxf(uv.z + gv.z, 0.0f) * vv.z;
            d += fmaxf(uv.w + gv.w, 0.0f) * vv.w;
        }
        for (int off = 32; off; off >>= 1) d += __shfl_down(d, off);
        if (lane == 0) row[B_SZ + s - 1] = c0 + d;
    }
    __syncthreads();

    float diag = row[b];
    float m = -3.4e38f;
    for (int j = tid; j < ROWLEN; j += 256) m = fmaxf(m, row[j]);
    for (int off = 32; off; off >>= 1) m = fmaxf(m, __shfl_down(m, off));
    if (lane == 0) redmax[wave] = m;
    __syncthreads();
    m = fmaxf(fmaxf(redmax[0], redmax[1]), fmaxf(redmax[2], redmax[3]));

    float es = 0.0f;
    int cnt = 0;
    for (int j = tid; j < ROWLEN; j += 256) {
        float x = row[j];
        es += __expf((x - m) * INV_T);
        if (x > diag) cnt++;
        else if (j < b && x == diag) cnt++;   // top_k tie-break: lower index wins
    }
    for (int off = 32; off; off >>= 1) {
        es += __shfl_down(es, off);
        cnt += __shfl_down(cnt, off);
    }
    __syncthreads();
    if (lane == 0) { redes[wave] = es; redcnt[wave] = cnt; }
    __syncthreads();
    if (tid == 0) {
        float esum = redes[0] + redes[1] + redes[2] + redes[3];
        int rank = redcnt[0] + redcnt[1] + redcnt[2] + redcnt[3];
        float loss_b = (m - diag) * INV_T + logf(esum);
        atomicAdd(&acc[0], loss_b);
        if (rank < 1) atomicAdd(&acc[1], 1.0f);
        if (rank < 3) atomicAdd(&acc[2], 1.0f);
        if (rank < 10) atomicAdd(&acc[3], 1.0f);
    }
}

__global__ void finalize_kernel(const float* __restrict__ acc, float* __restrict__ out) {
    int t = threadIdx.x;
    if (t < 4) out[t] = acc[t] * (1.0f / (float)B_SZ);
}

// ---------------------------------------------------------------------------
extern "C" void kernel_launch(void* const* d_in, const int* in_sizes, int n_in,
                              void* d_out, int out_size, void* d_ws, size_t ws_size,
                              hipStream_t stream) {
    const float* z          = (const float*)d_in[0];
    const float* z_next     = (const float*)d_in[1];
    const float* z_next_hat = (const float*)d_in[2];
    const float* actions    = (const float*)d_in[3];
    const float* Wa         = (const float*)d_in[4];
    const float* ba         = (const float*)d_in[5];
    const float* W1         = (const float*)d_in[6];
    const float* b1         = (const float*)d_in[7];
    const float* W2         = (const float*)d_in[8];
    const float* b2         = (const float*)d_in[9];
    float* out = (float*)d_out;

    float* ws  = (float*)d_ws;
    float* sim = ws;                         // 1024*1024
    float* u   = sim + B_SZ * B_SZ;          // 1024*512
    float* v   = u + B_SZ * ZH;              // 1024*512
    float* g   = v + B_SZ * ZH;              // 1024*512
    float* acc = g + B_SZ * ZH;              // 4

    hipMemsetAsync(acc, 0, 4 * sizeof(float), stream);

    fused_gemm<<<640, 256, 0, stream>>>(z, z_next, z_next_hat, actions, Wa, ba,
                                        W1, b1, W2, sim, u, v, g);
    row_kernel<<<B_SZ, 256, 0, stream>>>(sim, u, v, g, z, z_next, b2, acc);
    finalize_kernel<<<1, 64, 0, stream>>>(acc, out);
}

// Round 3
// 133.997 us; speedup vs baseline: 1.6383x; 1.0521x over previous
//
#include <hip/hip_runtime.h>
#include <math.h>

#define B_SZ 1024
#define Z_DIM 512
#define A_DIM 8
#define AH 64
#define ZH 512
#define NNEG 99
#define ROWLEN (B_SZ + NNEG)  // 1123
#define INV_T 10.0f

typedef __attribute__((ext_vector_type(8))) short short8;   // 8 bf16 (4 VGPRs)
typedef __attribute__((ext_vector_type(4))) float f32x4;

// Split fp32 -> bf16 hi (truncate) + bf16 lo (residual, truncated).
// a ~= hi + lo with rel error < 2^-16.
__device__ __forceinline__ void cvt_hilo(float4 x0, float4 x1, short8& hi, short8& lo) {
    float xs[8] = {x0.x, x0.y, x0.z, x0.w, x1.x, x1.y, x1.z, x1.w};
#pragma unroll
    for (int i = 0; i < 8; ++i) {
        unsigned u = __float_as_uint(xs[i]);
        hi[i] = (short)(u >> 16);
        float hf = __uint_as_float(u & 0xffff0000u);
        float lf = xs[i] - hf;
        lo[i] = (short)(__float_as_uint(lf) >> 16);
    }
}

// ---------------------------------------------------------------------------
// One launch, 640 blocks:
//   seg0 [  0,256): sim = z_next @ z_next_hat^T   [1024x1024 K=512]  (MFMA, NT)
//   seg1 [256,384): u   = z @ W1[:512,:] + b1     [1024x512  K=512]  (MFMA, NN)
//   seg2 [384,512): v   = z_next @ W2^T           [1024x512  K=512]  (MFMA, NT)
//   seg3 [512,640): g   = relu(actions@Wa+ba)@W1h [1024x512  K=64]   (fp32 vector)
// MFMA path: 64x64 tile, 4 waves each 32x32 (2x2 of 16x16x32 bf16 tiles),
// 3-term hi/lo split for ~fp32 accuracy. Also zeroes the row-kernel counter.
__global__ __launch_bounds__(256) void fused_gemm(
    const float* __restrict__ z, const float* __restrict__ z_next,
    const float* __restrict__ z_next_hat, const float* __restrict__ actions,
    const float* __restrict__ Wa, const float* __restrict__ ba,
    const float* __restrict__ W1, const float* __restrict__ b1,
    const float* __restrict__ W2,
    float* __restrict__ sim, float* __restrict__ u, float* __restrict__ v,
    float* __restrict__ g, unsigned* __restrict__ cnt)
{
    __shared__ float LA[64][68];   // [m][k] fp32, stride 68 (272B, 16B-aligned)
    __shared__ float LB[64][68];   // [n][k] fp32
    __shared__ float sact[64][A_DIM];
    __shared__ float sWa[A_DIM * AH];
    __shared__ float sba[AH];

    const int id = blockIdx.x;
    const int tid = threadIdx.x;
    if (id == 0 && tid == 0) *cnt = 0;   // for row_kernel's last-block pattern

    // ================= seg3: g (fp32 vector path, K=64) =================
    if (id >= 512) {
        int t = id - 512;
        int bn0 = (t & 7) * 64, bm0 = (t >> 3) * 64;
        const float* W1h = W1 + Z_DIM * ZH;
        for (int i = tid; i < 64 * A_DIM; i += 256)
            (&sact[0][0])[i] = actions[bm0 * A_DIM + i];
        for (int i = tid; i < A_DIM * AH; i += 256) sWa[i] = Wa[i];
        if (tid < AH) sba[tid] = ba[tid];
        __syncthreads();
        int tm = (tid >> 4) << 2, tn = (tid & 15) << 2;
        float acc[4][4] = {};
        for (int k0 = 0; k0 < 64; k0 += 32) {
#pragma unroll
            for (int i = 0; i < 8; ++i) {           // A-tile gen: As[k][m] in LA
                int lin = tid + i * 256;
                int c = lin & 31, r = lin >> 5;
                int kc = k0 + c;
                float val = sba[kc];
#pragma unroll
                for (int k = 0; k < A_DIM; ++k) val += sact[r][k] * sWa[k * AH + kc];
                LA[c][r] = fmaxf(val, 0.0f);
            }
#pragma unroll
            for (int i = 0; i < 2; ++i) {           // B-tile: Bs[k][n] in LB
                int f = tid + i * 256;
                int r = f >> 4, c = (f & 15) * 4;
                *(float4*)&LB[r][c] = *(const float4*)&W1h[(k0 + r) * ZH + bn0 + c];
            }
            __syncthreads();
#pragma unroll
            for (int k = 0; k < 32; ++k) {
                float4 a4 = *(const float4*)&LA[k][tm];
                float4 b4 = *(const float4*)&LB[k][tn];
                float a[4] = {a4.x, a4.y, a4.z, a4.w};
                float b[4] = {b4.x, b4.y, b4.z, b4.w};
#pragma unroll
                for (int i = 0; i < 4; ++i)
#pragma unroll
                    for (int j = 0; j < 4; ++j) acc[i][j] += a[i] * b[j];
            }
            __syncthreads();
        }
#pragma unroll
        for (int i = 0; i < 4; ++i) {
            float4 o = {acc[i][0], acc[i][1], acc[i][2], acc[i][3]};
            *(float4*)&g[(bm0 + tm + i) * ZH + bn0 + tn] = o;
        }
        return;
    }

    // ================= MFMA segs =================
    const float* Aop; const float* Bop; const float* bias = nullptr;
    float* C; int N; bool btrans; int bm0, bn0;
    if (id < 256) {
        int t = id; bn0 = (t & 15) * 64; bm0 = (t >> 4) * 64;
        Aop = z_next; Bop = z_next_hat; C = sim; N = 1024; btrans = true;
    } else if (id < 384) {
        int t = id - 256; bn0 = (t & 7) * 64; bm0 = (t >> 3) * 64;
        Aop = z; Bop = W1; C = u; N = 512; btrans = false; bias = b1;
    } else {
        int t = id - 384; bn0 = (t & 7) * 64; bm0 = (t >> 3) * 64;
        Aop = z_next; Bop = W2; C = v; N = 512; btrans = true;
    }

    const int lane = tid & 63, wv = tid >> 6;
    const int lm = lane & 15, lq = lane >> 4;       // tile row/col pieces
    const int wm = (wv >> 1) * 32, wn = (wv & 1) * 32;
    f32x4 acc[2][2] = {};

    for (int k0 = 0; k0 < 512; k0 += 64) {
        // stage A: LA[m][k] via float4 (row-major NT source)
#pragma unroll
        for (int i = 0; i < 4; ++i) {
            int gg = tid + i * 256;
            int r = gg >> 4, c4 = (gg & 15) << 2;
            *(float4*)&LA[r][c4] = *(const float4*)&Aop[(bm0 + r) * 512 + k0 + c4];
        }
        if (btrans) {
#pragma unroll
            for (int i = 0; i < 4; ++i) {
                int gg = tid + i * 256;
                int r = gg >> 4, c4 = (gg & 15) << 2;
                *(float4*)&LB[r][c4] = *(const float4*)&Bop[(bn0 + r) * 512 + k0 + c4];
            }
        } else {  // k-major source (W1): transpose in LDS
#pragma unroll
            for (int i = 0; i < 4; ++i) {
                int gg = tid + i * 256;
                int kr = gg >> 4, n4 = (gg & 15) << 2;
                float4 w = *(const float4*)&Bop[(k0 + kr) * 512 + bn0 + n4];
                LB[n4 + 0][kr] = w.x; LB[n4 + 1][kr] = w.y;
                LB[n4 + 2][kr] = w.z; LB[n4 + 3][kr] = w.w;
            }
        }
        __syncthreads();
#pragma unroll
        for (int kk = 0; kk < 64; kk += 32) {
            int kb = kk + lq * 8;
            short8 ah[2], al[2], bh[2], bl[2];
#pragma unroll
            for (int i = 0; i < 2; ++i) {
                float4 x0 = *(const float4*)&LA[wm + i * 16 + lm][kb];
                float4 x1 = *(const float4*)&LA[wm + i * 16 + lm][kb + 4];
                cvt_hilo(x0, x1, ah[i], al[i]);
                float4 y0 = *(const float4*)&LB[wn + i * 16 + lm][kb];
                float4 y1 = *(const float4*)&LB[wn + i * 16 + lm][kb + 4];
                cvt_hilo(y0, y1, bh[i], bl[i]);
            }
#pragma unroll
            for (int i = 0; i < 2; ++i)
#pragma unroll
                for (int j = 0; j < 2; ++j) {
                    acc[i][j] = __builtin_amdgcn_mfma_f32_16x16x32_bf16(ah[i], bh[j], acc[i][j], 0, 0, 0);
                    acc[i][j] = __builtin_amdgcn_mfma_f32_16x16x32_bf16(ah[i], bl[j], acc[i][j], 0, 0, 0);
                    acc[i][j] = __builtin_amdgcn_mfma_f32_16x16x32_bf16(al[i], bh[j], acc[i][j], 0, 0, 0);
                }
        }
        __syncthreads();
    }
    // epilogue: C layout col=lane&15, row=(lane>>4)*4+reg  [m89/m91 verified]
#pragma unroll
    for (int i = 0; i < 2; ++i)
#pragma unroll
        for (int j = 0; j < 2; ++j) {
            int n = bn0 + wn + j * 16 + lm;
            float bb = bias ? bias[n] : 0.0f;
#pragma unroll
            for (int r = 0; r < 4; ++r) {
                int m = bm0 + wm + i * 16 + lq * 4 + r;
                C[m * N + n] = acc[i][j][r] + bb;
            }
        }
}

// ---------------------------------------------------------------------------
// Per-row fused kernel + last-block finalize (no hot atomics, 1 per block).
__global__ __launch_bounds__(256) void row_kernel(const float* __restrict__ sim,
                                                  const float* __restrict__ u,
                                                  const float* __restrict__ v,
                                                  const float* __restrict__ g,
                                                  const float* __restrict__ z,
                                                  const float* __restrict__ z_next,
                                                  const float* __restrict__ b2,
                                                  float* __restrict__ pw,
                                                  unsigned* __restrict__ cnt,
                                                  float* __restrict__ out) {
    int b = blockIdx.x;
    int tid = threadIdx.x;
    int wave = tid >> 6, lane = tid & 63;
    __shared__ float su[ZH];
    __shared__ float sv[ZH];
    __shared__ float row[ROWLEN];
    __shared__ float redc0[4], redmax[4], redes[4];
    __shared__ int redcnt[4];
    __shared__ float red[256];
    __shared__ int sdone;

    {
        const float4* u4 = (const float4*)(u + b * ZH);
        const float4* v4 = (const float4*)(v + b * ZH);
        if (tid < ZH / 4) {
            *(float4*)&su[tid * 4] = u4[tid];
            *(float4*)&sv[tid * 4] = v4[tid];
        }
        const float4* s4 = (const float4*)(sim + b * B_SZ);
        *(float4*)&row[tid * 4] = s4[tid];
    }
    float p = 0.0f;
    {
        const float4* z4 = (const float4*)(z + b * Z_DIM);
        const float4* zn4 = (const float4*)(z_next + b * Z_DIM);
        const float4* b24 = (const float4*)b2;
        if (tid < Z_DIM / 4) {
            float4 a = z4[tid], c = b24[tid], n = zn4[tid];
            p = (a.x + c.x) * n.x + (a.y + c.y) * n.y + (a.z + c.z) * n.z + (a.w + c.w) * n.w;
        }
    }
    for (int off = 32; off; off >>= 1) p += __shfl_down(p, off);
    if (lane == 0) redc0[wave] = p;
    __syncthreads();

    float c0 = redc0[0] + redc0[1] + redc0[2] + redc0[3];

    for (int s = 1 + wave; s <= NNEG; s += 4) {
        int jr = (b + s) & (B_SZ - 1);
        const float4* gr4 = (const float4*)(g + jr * ZH);
        float d = 0.0f;
#pragma unroll
        for (int i = 0; i < 2; ++i) {
            int t4 = lane + i * 64;
            float4 gv = gr4[t4];
            float4 uv = *(const float4*)&su[t4 * 4];
            float4 vv = *(const float4*)&sv[t4 * 4];
            d += fmaxf(uv.x + gv.x, 0.0f) * vv.x;
            d += fmaxf(uv.y + gv.y, 0.0f) * vv.y;
            d += fmaxf(uv.z + gv.z, 0.0f) * vv.z;
            d += fmaxf(uv.w + gv.w, 0.0f) * vv.w;
        }
        for (int off = 32; off; off >>= 1) d += __shfl_down(d, off);
        if (lane == 0) row[B_SZ + s - 1] = c0 + d;
    }
    __syncthreads();

    float diag = row[b];
    float m = -3.4e38f;
    for (int j = tid; j < ROWLEN; j += 256) m = fmaxf(m, row[j]);
    for (int off = 32; off; off >>= 1) m = fmaxf(m, __shfl_down(m, off));
    if (lane == 0) redmax[wave] = m;
    __syncthreads();
    m = fmaxf(fmaxf(redmax[0], redmax[1]), fmaxf(redmax[2], redmax[3]));

    float es = 0.0f;
    int cntk = 0;
    for (int j = tid; j < ROWLEN; j += 256) {
        float x = row[j];
        es += __expf((x - m) * INV_T);
        if (x > diag) cntk++;
        else if (j < b && x == diag) cntk++;   // tie-break: lower index wins
    }
    for (int off = 32; off; off >>= 1) {
        es += __shfl_down(es, off);
        cntk += __shfl_down(cntk, off);
    }
    __syncthreads();
    if (lane == 0) { redes[wave] = es; redcnt[wave] = cntk; }
    __syncthreads();
    if (tid == 0) {
        float esum = redes[0] + redes[1] + redes[2] + redes[3];
        int rank = redcnt[0] + redcnt[1] + redcnt[2] + redcnt[3];
        float loss_b = (m - diag) * INV_T + logf(esum);
        pw[b * 4 + 0] = loss_b;
        pw[b * 4 + 1] = (rank < 1) ? 1.0f : 0.0f;
        pw[b * 4 + 2] = (rank < 3) ? 1.0f : 0.0f;
        pw[b * 4 + 3] = (rank < 10) ? 1.0f : 0.0f;
        __threadfence();
        unsigned old = atomicAdd(cnt, 1u);
        sdone = (old == B_SZ - 1) ? 1 : 0;
    }
    __syncthreads();
    if (sdone) {
        __threadfence();   // acquire: see all blocks' pw stores
        int c = tid & 3;
        float s = 0.0f;
        for (int r = tid >> 2; r < B_SZ; r += 64) s += pw[r * 4 + c];
        red[tid] = s;
        __syncthreads();
        if (tid < 4) {
            float t = 0.0f;
            for (int gg = 0; gg < 64; ++gg) t += red[tid + gg * 4];
            out[tid] = t * (1.0f / (float)B_SZ);
        }
    }
}

// ---------------------------------------------------------------------------
extern "C" void kernel_launch(void* const* d_in, const int* in_sizes, int n_in,
                              void* d_out, int out_size, void* d_ws, size_t ws_size,
                              hipStream_t stream) {
    const float* z          = (const float*)d_in[0];
    const float* z_next     = (const float*)d_in[1];
    const float* z_next_hat = (const float*)d_in[2];
    const float* actions    = (const float*)d_in[3];
    const float* Wa         = (const float*)d_in[4];
    const float* ba         = (const float*)d_in[5];
    const float* W1         = (const float*)d_in[6];
    const float* b1         = (const float*)d_in[7];
    const float* W2         = (const float*)d_in[8];
    const float* b2         = (const float*)d_in[9];
    float* out = (float*)d_out;

    float* ws  = (float*)d_ws;
    float* sim = ws;                         // 1024*1024
    float* u   = sim + B_SZ * B_SZ;          // 1024*512
    float* v   = u + B_SZ * ZH;              // 1024*512
    float* g   = v + B_SZ * ZH;              // 1024*512
    float* pw  = g + B_SZ * ZH;              // 1024*4
    unsigned* cnt = (unsigned*)(pw + B_SZ * 4);

    fused_gemm<<<640, 256, 0, stream>>>(z, z_next, z_next_hat, actions, Wa, ba,
                                        W1, b1, W2, sim, u, v, g, cnt);
    row_kernel<<<B_SZ, 256, 0, stream>>>(sim, u, v, g, z, z_next, b2, pw, cnt, out);
}